// Round 11
// baseline (111.496 us; speedup 1.0000x reference)
//
#include <hip/hip_runtime.h>
#include <stdint.h>

typedef _Float16 half8 __attribute__((ext_vector_type(8)));
typedef __fp16 fp16x2 __attribute__((ext_vector_type(2)));
typedef float f32x4 __attribute__((ext_vector_type(4)));
typedef float f32x2 __attribute__((ext_vector_type(2)));
typedef uint32_t u32x2 __attribute__((ext_vector_type(2)));

#define N_ 32
#define C_ 8
#define W_ 65536
#define F_ 16
#define OW_ 65473
#define K_ 512
#define TILE_T 512
#define NT_ 4                // tiles per persistent block
#define XS 576               // halfs per channel row in x LDS (512 + 64 halo)
#define SCP 140              // scratch row stride in floats
#define SCW 4480             // scratch bytes per wave (8 rows * 560 B)

// funnel16(hi, lo) = (hi:lo) >> 16  -> v_alignbit_b32
__device__ __forceinline__ uint32_t funnel16(uint32_t hi, uint32_t lo) {
  return (uint32_t)((((uint64_t)hi << 32) | (uint64_t)lo) >> 16);
}

// pack two f32 -> one dword of 2x f16 (v_cvt_pkrtz_f16_f32)
__device__ __forceinline__ uint32_t pk(float a, float b) {
  union { fp16x2 h; uint32_t u; } cv;
  cv.h = __builtin_amdgcn_cvt_pkrtz(a, b);
  return cv.u;
}

__device__ __forceinline__ f32x4 ldx(const float* p) {
  return *reinterpret_cast<const f32x4*>(p);
}

// Persistent block: one n, 4 consecutive 512-t tiles, w held in registers
// (wf[16], loaded once -> kills the wf ds_read (33% of K-loop LDS traffic)
// and the per-block w re-stage). Per tile: stage x f16 -> bar -> K-loop
// (win reads only) -> bar -> line-exact epilogue (scratch overlays dead xb)
// -> bar. Mapping (validated R1-R9): t = t0 + tlw + r + 8*c15, f = 4*g + q.
template<bool TAILB>
__device__ __forceinline__ void block_job(const float* __restrict__ x,
                                          const float* __restrict__ w,
                                          const float* __restrict__ b,
                                          float* __restrict__ out,
                                          char* smem, int n, int tb0) {
  _Float16* xb = reinterpret_cast<_Float16*>(smem);   // 9216 B... (C_*XS*2)

  const int tid  = threadIdx.x;
  const int lane = tid & 63;
  const int wv   = tid >> 6;           // 0..3
  const int c15  = lane & 15;
  const int g    = lane >> 4;
  const int tlw  = wv << 7;            // wave's 128-t slice of the 512 tile

  const float* xn = x + (size_t)n * (C_ * W_);
  float* outn = out + (size_t)n * F_ * OW_;

  // ---- w -> registers, once per block (scattered but L2-hot) ----
  half8 wf[16];
  {
    const float* wrow = w + c15 * K_ + 8 * g;
    #pragma unroll
    for (int s = 0; s < 16; ++s) {
      f32x4 a = ldx(wrow + 32 * s);
      f32x4 c = ldx(wrow + 32 * s + 4);
      union { uint32_t d[4]; half8 h; } u;
      u.d[0] = pk(a[0], a[1]); u.d[1] = pk(a[2], a[3]);
      u.d[2] = pk(c[0], c[1]); u.d[3] = pk(c[2], c[3]);
      wf[s] = u.h;
    }
  }
  const f32x4 bv = *reinterpret_cast<const f32x4*>(b + 4 * g);

  union Win { half8 h[2]; uint32_t d[8]; };

  for (int it = 0; it < NT_; ++it) {
    const int t0 = tb0 + it * TILE_T;
    const bool tail = TAILB && (it == NT_ - 1);

    if (it) __syncthreads();           // scratch (in xb) done before re-stage

    // ---- stage x: 1152 f32x4 units = 8 ch x 144 (576 halfs/ch) ----
    #pragma unroll
    for (int j = 0; j < 5; ++j) {
      int u = tid + 256 * j;
      if (j == 4 && u >= 1152) break;  // 5th pass: 128 threads
      int ch = u / 144;
      int pos = (u - ch * 144) * 4;    // 0..572
      int gi = t0 + pos;
      f32x4 v;
      if (tail) v = (gi < W_) ? ldx(xn + (size_t)ch * W_ + gi) : (f32x4){0.f,0.f,0.f,0.f};
      else      v = ldx(xn + (size_t)ch * W_ + gi);
      u32x2 p; p[0] = pk(v[0], v[1]); p[1] = pk(v[2], v[3]);
      *reinterpret_cast<u32x2*>(reinterpret_cast<char*>(xb) +
                                (size_t)(ch * XS + pos) * 2u) = p;
    }

    __syncthreads();

    f32x4 acc[8];
    #pragma unroll
    for (int r = 0; r < 8; ++r) acc[r] = (f32x4){0.f, 0.f, 0.f, 0.f};

    // ---- K loop: 16 k-steps x 8 MFMA; x window from LDS, w from regs ----
    #pragma unroll
    for (int s = 0; s < 16; ++s) {
      const int c  = s >> 1;
      const int jb = (s & 1) * 32;
      const int A0 = tlw + 8 * c15 + jb + 8 * g;   // mult of 8 -> 16B aligned
      Win win;
      win.h[0] = *reinterpret_cast<const half8*>(xb + c * XS + A0);
      win.h[1] = *reinterpret_cast<const half8*>(xb + c * XS + A0 + 8);
      #pragma unroll
      for (int r = 0; r < 8; ++r) {
        union { uint32_t d[4]; half8 h; } fr;
        const int m = r >> 1;
        if ((r & 1) == 0) {
          fr.d[0] = win.d[m];     fr.d[1] = win.d[m + 1];
          fr.d[2] = win.d[m + 2]; fr.d[3] = win.d[m + 3];
        } else {
          fr.d[0] = funnel16(win.d[m + 1], win.d[m]);
          fr.d[1] = funnel16(win.d[m + 2], win.d[m + 1]);
          fr.d[2] = funnel16(win.d[m + 3], win.d[m + 2]);
          fr.d[3] = funnel16(win.d[m + 4], win.d[m + 3]);
        }
        acc[r] = __builtin_amdgcn_mfma_f32_16x16x32_f16(wf[s], fr.h, acc[r], 0, 0, 0);
      }
    }

    __syncthreads();   // xb dead -> reuse as per-wave transpose scratch

    // ---- epilogue: per-wave LDS transpose -> line-exact stores ----
    float* sc = reinterpret_cast<float*>(smem + (size_t)wv * SCW);
    const int Tw  = t0 + tlw;          // multiple of 128
    const int flr = lane >> 3;         // read role: f-row 0..7
    const int k   = lane & 7;          // read role: 8 lanes per row

    #pragma unroll
    for (int cb = 0; cb < 2; ++cb) {
      const int qb = 2 * cb;
      #pragma unroll
      for (int dq = 0; dq < 2; ++dq) {
        const int q  = qb + dq;
        const int fl = 2 * g + dq;
        const float bias = 8.0f * bv[q];   // reference adds bias C times
        f32x4 lo = { acc[0][q] + bias, acc[1][q] + bias,
                     acc[2][q] + bias, acc[3][q] + bias };
        f32x4 hi = { acc[4][q] + bias, acc[5][q] + bias,
                     acc[6][q] + bias, acc[7][q] + bias };
        *reinterpret_cast<f32x4*>(sc + fl * SCP + 8 * c15)     = lo;
        *reinterpret_cast<f32x4*>(sc + fl * SCP + 8 * c15 + 4) = hi;
      }
      // row f; 64B groups start at tf so each 8-lane f32x2 group = one line
      const int f  = 4 * (flr >> 1) + qb + (flr & 1);
      const int tf = (16 - f) & 15;
      float* row = outn + (size_t)f * OW_ + Tw;
      #pragma unroll
      for (int j = 0; j < 7; ++j) {
        const int t = tf + 2 * k + 16 * j;
        f32x2 v = { sc[flr * SCP + t], sc[flr * SCP + t + 1] };
        if (!tail || Tw + t + 2 <= OW_) {
          *reinterpret_cast<f32x2*>(row + t) = v;
        } else {
          if (Tw + t     < OW_) row[t]     = v[0];
          if (Tw + t + 1 < OW_) row[t + 1] = v[1];
        }
      }
      #pragma unroll
      for (int e2 = 0; e2 < 2; ++e2) {
        const int e = k + 8 * e2;
        const int t = (e < tf) ? e : 112 + e;
        if (!tail || Tw + t < OW_) row[t] = sc[flr * SCP + t];
      }
    }
  }
}

__global__ __launch_bounds__(256, 4)
void corr1d(const float* __restrict__ x, const float* __restrict__ w,
            const float* __restrict__ b, float* __restrict__ out) {
  __shared__ __align__(16) char smem[18432];   // xb (9216 halfs) / scratch 17.9K

  const int n  = blockIdx.x >> 5;      // 32 n
  const int bt = blockIdx.x & 31;      // 32 blocks of 2048 t (4 tiles)
  const int tb0 = bt << 11;

  if (bt < 31) block_job<false>(x, w, b, out, smem, n, tb0);
  else         block_job<true >(x, w, b, out, smem, n, tb0);
}

extern "C" void kernel_launch(void* const* d_in, const int* in_sizes, int n_in,
                              void* d_out, int out_size, void* d_ws, size_t ws_size,
                              hipStream_t stream) {
  (void)in_sizes; (void)n_in; (void)out_size; (void)d_ws; (void)ws_size;
  const float* x = (const float*)d_in[0];
  const float* w = (const float*)d_in[1];
  const float* b = (const float*)d_in[2];
  float* out = (float*)d_out;
  corr1d<<<dim3(32 * 32), dim3(256), 0, stream>>>(x, w, b, out);
}

// Round 12
// 61.398 us; speedup vs baseline: 1.8160x; 1.8160x over previous
//
#include <hip/hip_runtime.h>
#include <stdint.h>

typedef _Float16 half8 __attribute__((ext_vector_type(8)));
typedef __fp16 fp16x2 __attribute__((ext_vector_type(2)));
typedef float f32x4 __attribute__((ext_vector_type(4)));
typedef float f32x2 __attribute__((ext_vector_type(2)));
typedef uint32_t u32x2 __attribute__((ext_vector_type(2)));

#define C_ 8
#define W_ 65536
#define F_ 16
#define OW_ 65473
#define K_ 512
#define TILE 512
#define XH 576               // halfs per channel row (512 + 64 halo), exact
#define SCP 140              // scratch row stride (floats)

// funnel16(hi, lo) = (hi:lo) >> 16  -> v_alignbit_b32
__device__ __forceinline__ uint32_t funnel16(uint32_t hi, uint32_t lo) {
  return (uint32_t)((((uint64_t)hi << 32) | (uint64_t)lo) >> 16);
}
// pack two f32 -> one dword of 2x f16 (v_cvt_pkrtz_f16_f32)
__device__ __forceinline__ uint32_t pk(float a, float b) {
  union { fp16x2 h; uint32_t u; } cv;
  cv.h = __builtin_amdgcn_cvt_pkrtz(a, b);
  return cv.u;
}
// w LDS swizzle (half-index, mult of 4)
__device__ __forceinline__ uint32_t wswz(uint32_t e) {
  uint32_t ch = e >> 3;
  ch ^= (ch >> 6) & 7u;
  return (ch << 4) | ((e & 7u) << 1);
}
__device__ __forceinline__ f32x4 ldx(const float* p) {
  return *reinterpret_cast<const f32x4*>(p);
}

// lgkm-only workgroup barrier: LDS writes visible, but global loads/stores
// stay IN FLIGHT across it (no vmcnt(0) drain — the __syncthreads tax).
__device__ __forceinline__ void wg_barrier() {
  __builtin_amdgcn_sched_barrier(0);
  asm volatile("s_waitcnt lgkmcnt(0)" ::: "memory");
  __builtin_amdgcn_sched_barrier(0);
  __builtin_amdgcn_s_barrier();
  __builtin_amdgcn_sched_barrier(0);
}

// K loop: 16 k-steps x 8 MFMA; w frag from swizzled LDS, x window 2x b128.
// Mapping (validated R1-R10): t = t0 + tlw + r + 8*c15, f = 4*g + q.
__device__ __forceinline__ void kloop(const _Float16* __restrict__ wl,
                                      const _Float16* __restrict__ xb,
                                      f32x4 acc[8], int c15, int g, int tlw) {
  union Win { half8 h[2]; uint32_t d[8]; };
  #pragma unroll
  for (int s = 0; s < 16; ++s) {
    const uint32_t we = (uint32_t)(c15 * K_ + 32 * s + 8 * g);
    const half8 wf = *reinterpret_cast<const half8*>(
                         reinterpret_cast<const char*>(wl) + wswz(we));
    const int c  = s >> 1;
    const int jb = (s & 1) * 32;
    const int A0 = tlw + 8 * c15 + jb + 8 * g;   // mult of 8 -> 16B aligned
    Win win;
    win.h[0] = *reinterpret_cast<const half8*>(xb + c * XH + A0);
    win.h[1] = *reinterpret_cast<const half8*>(xb + c * XH + A0 + 8);
    #pragma unroll
    for (int r = 0; r < 8; ++r) {
      union { uint32_t d[4]; half8 h; } fr;
      const int m = r >> 1;
      if ((r & 1) == 0) {
        fr.d[0] = win.d[m];     fr.d[1] = win.d[m + 1];
        fr.d[2] = win.d[m + 2]; fr.d[3] = win.d[m + 3];
      } else {
        fr.d[0] = funnel16(win.d[m + 1], win.d[m]);
        fr.d[1] = funnel16(win.d[m + 2], win.d[m + 1]);
        fr.d[2] = funnel16(win.d[m + 3], win.d[m + 2]);
        fr.d[3] = funnel16(win.d[m + 4], win.d[m + 3]);
      }
      acc[r] = __builtin_amdgcn_mfma_f32_16x16x32_f16(wf, fr.h, acc[r], 0, 0, 0);
    }
  }
}

// Epilogue: per-wave LDS transpose (scratch = dead x buffer, per-wave slice,
// no cross-wave sync) -> even-t f32x2 stores (<=12.5% line-cross on odd f).
template<bool TAILT>
__device__ __forceinline__ void epilogue(const f32x4 acc[8], f32x4 bv,
                                         float* __restrict__ outn,
                                         float* __restrict__ scw,
                                         int Tw, int lane) {
  const int c15 = lane & 15;
  const int g   = lane >> 4;
  #pragma unroll
  for (int q = 0; q < 4; ++q) {
    const float bias = 8.0f * bv[q];   // reference adds bias C times
    f32x4 lo = { acc[0][q] + bias, acc[1][q] + bias,
                 acc[2][q] + bias, acc[3][q] + bias };
    f32x4 hi = { acc[4][q] + bias, acc[5][q] + bias,
                 acc[6][q] + bias, acc[7][q] + bias };
    *reinterpret_cast<f32x4*>(scw + g * SCP + 8 * c15)     = lo;
    *reinterpret_cast<f32x4*>(scw + g * SCP + 8 * c15 + 4) = hi;
    // same-wave DS ops are memory-side in-order; compiler orders via aliasing
    const int f = 4 * g + q;
    float* row = outn + (size_t)f * OW_ + Tw;
    #pragma unroll
    for (int p = 0; p < 4; ++p) {
      const int t = 2 * c15 + 32 * p;
      f32x2 v = { scw[g * SCP + t], scw[g * SCP + t + 1] };
      if (!TAILT || Tw + t + 2 <= OW_) {
        *reinterpret_cast<f32x2*>(row + t) = v;
      } else {
        if (Tw + t     < OW_) row[t]     = v[0];
        if (Tw + t + 1 < OW_) row[t + 1] = v[1];
      }
    }
  }
}

// Block = two 512-t tiles of one n, double-buffered f16 x LDS.
// stage w + x0, issue prefetch(x1)->regs | bar | K(0) , cvt->xb1 | bar |
// epi(0) [stores drain under...] K(1) | bar | epi(1).  No vmcnt(0) anywhere.
template<bool TAILB>
__device__ __forceinline__ void block_job(const float* __restrict__ x,
                                          const float* __restrict__ w,
                                          const float* __restrict__ b,
                                          float* __restrict__ out,
                                          char* smem, int n, int t0) {
  _Float16* wl  = reinterpret_cast<_Float16*>(smem);            // 16384 B
  _Float16* xb0 = reinterpret_cast<_Float16*>(smem + 16384);    // 9216 B
  _Float16* xb1 = reinterpret_cast<_Float16*>(smem + 16384 + 9216);

  const int tid  = threadIdx.x;
  const int lane = tid & 63;
  const int wv   = tid >> 6;           // 0..3
  const int c15  = lane & 15;
  const int g    = lane >> 4;
  const int tlw  = wv << 7;

  const float* xn = x + (size_t)n * (C_ * W_);
  float* outn = out + (size_t)n * F_ * OW_;

  // ---- stage w: 8192 f32 -> f16 swizzled ----
  #pragma unroll
  for (int j = 0; j < 8; ++j) {
    int e = (tid + 256 * j) * 4;
    f32x4 v = ldx(w + e);
    u32x2 p; p[0] = pk(v[0], v[1]); p[1] = pk(v[2], v[3]);
    *reinterpret_cast<u32x2*>(reinterpret_cast<char*>(wl) + wswz((uint32_t)e)) = p;
  }
  // ---- stage x tile0 direct (never tail) ----
  #pragma unroll
  for (int j = 0; j < 5; ++j) {
    int u = tid + 256 * j;
    if (j == 4 && u >= 1152) break;
    int ch = u / 144; int pos = (u - ch * 144) * 4;
    f32x4 v = ldx(xn + (size_t)ch * W_ + t0 + pos);
    u32x2 p; p[0] = pk(v[0], v[1]); p[1] = pk(v[2], v[3]);
    *reinterpret_cast<u32x2*>(reinterpret_cast<char*>(xb0) +
                              (size_t)(ch * XH + pos) * 2u) = p;
  }
  // ---- issue prefetch tile1 -> regs (in flight across K(0)) ----
  f32x4 pre[5];
  const int t1 = t0 + TILE;
  #pragma unroll
  for (int j = 0; j < 5; ++j) {
    int u = tid + 256 * j;
    if (j == 4 && u >= 1152) break;
    int ch = u / 144; int pos = (u - ch * 144) * 4;
    int gi = t1 + pos;
    if (TAILB) pre[j] = (gi < W_) ? ldx(xn + (size_t)ch * W_ + gi)
                                  : (f32x4){0.f, 0.f, 0.f, 0.f};
    else       pre[j] = ldx(xn + (size_t)ch * W_ + gi);
  }
  const f32x4 bv = *reinterpret_cast<const f32x4*>(b + 4 * g);

  wg_barrier();              // w + x0 visible; prefetch loads NOT drained

  f32x4 acc[8];
  #pragma unroll
  for (int r = 0; r < 8; ++r) acc[r] = (f32x4){0.f, 0.f, 0.f, 0.f};
  kloop(wl, xb0, acc, c15, g, tlw);

  // cvt prefetch -> xb1 (no hazard: K reads xb0; vmcnt waits auto-inserted)
  #pragma unroll
  for (int j = 0; j < 5; ++j) {
    int u = tid + 256 * j;
    if (j == 4 && u >= 1152) break;
    int ch = u / 144; int pos = (u - ch * 144) * 4;
    u32x2 p; p[0] = pk(pre[j][0], pre[j][1]); p[1] = pk(pre[j][2], pre[j][3]);
    *reinterpret_cast<u32x2*>(reinterpret_cast<char*>(xb1) +
                              (size_t)(ch * XH + pos) * 2u) = p;
  }

  wg_barrier();              // all waves past K(xb0); xb1 writes visible

  // epilogue(0) first: its stores drain under K(1). scratch = per-wave
  // slice of dead xb0 (4 rows * 560 B = 2240 B/wave, 8960 <= 9216).
  epilogue<false>(acc, bv, outn,
                  reinterpret_cast<float*>(reinterpret_cast<char*>(xb0) + wv * 2240),
                  t0 + tlw, lane);

  f32x4 acc2[8];
  #pragma unroll
  for (int r = 0; r < 8; ++r) acc2[r] = (f32x4){0.f, 0.f, 0.f, 0.f};
  kloop(wl, xb1, acc2, c15, g, tlw);

  wg_barrier();              // all waves past K(xb1) before scratch overlays it

  epilogue<TAILB>(acc2, bv, outn,
                  reinterpret_cast<float*>(reinterpret_cast<char*>(xb1) + wv * 2240),
                  t1 + tlw, lane);
}

__global__ __launch_bounds__(256, 4)
void corr1d(const float* __restrict__ x, const float* __restrict__ w,
            const float* __restrict__ b, float* __restrict__ out) {
  __shared__ __align__(16) char smem[16384 + 2 * 9216];   // 34816 B

  const int n  = blockIdx.x >> 6;      // 32 n
  const int bt = blockIdx.x & 63;      // 64 blocks of 1024 t (2 tiles)
  const int t0 = bt << 10;

  if (bt < 63) block_job<false>(x, w, b, out, smem, n, t0);
  else         block_job<true >(x, w, b, out, smem, n, t0);
}

extern "C" void kernel_launch(void* const* d_in, const int* in_sizes, int n_in,
                              void* d_out, int out_size, void* d_ws, size_t ws_size,
                              hipStream_t stream) {
  (void)in_sizes; (void)n_in; (void)out_size; (void)d_ws; (void)ws_size;
  const float* x = (const float*)d_in[0];
  const float* w = (const float*)d_in[1];
  const float* b = (const float*)d_in[2];
  float* out = (float*)d_out;
  corr1d<<<dim3(32 * 64), dim3(256), 0, stream>>>(x, w, b, out);
}